// Round 1
// baseline (677.512 us; speedup 1.0000x reference)
//
#include <hip/hip_runtime.h>

// AsynchronousGRUActor fused kernel — MI355X gfx950.
// Strategy: bf16 MFMA (16x16x32) for all four matmuls, one wave = 16 rows,
// weights pre-converted to bf16 in d_ws, activations converted inline.
// Only LDS use: per-wave 16x72 bf16 buffer for C-layout -> A-layout hops.

#define BB   500000
#define OBSN 128
#define HD   64
#define ADIM 16

typedef __attribute__((ext_vector_type(8))) short short8;
typedef __attribute__((ext_vector_type(4))) float f32x4;

__device__ __forceinline__ unsigned short f2b(float f) {
  union { float f; unsigned u; } c; c.f = f;
  return (unsigned short)((c.u + 0x7fffu + ((c.u >> 16) & 1u)) >> 16);  // RNE
}
__device__ __forceinline__ unsigned pk2(float a, float b) {
  return (unsigned)f2b(a) | ((unsigned)f2b(b) << 16);
}
__device__ __forceinline__ short8 cvt_frag(float4 a, float4 b) {
  union { short8 v; unsigned u[4]; } t;
  t.u[0] = pk2(a.x, a.y); t.u[1] = pk2(a.z, a.w);
  t.u[2] = pk2(b.x, b.y); t.u[3] = pk2(b.z, b.w);
  return t.v;
}
__device__ __forceinline__ short8 load_cvt_frag(const float* __restrict__ p) {
  float4 a = *(const float4*)p;
  float4 b = *(const float4*)(p + 4);
  return cvt_frag(a, b);
}
__device__ __forceinline__ float fsigmoid(float x) {
  return __builtin_amdgcn_rcpf(1.f + __builtin_amdgcn_exp2f(-1.44269504f * x));
}
__device__ __forceinline__ float ftanh(float x) {
  // tanh(x) = 1 - 2/(exp2(2x*log2e)+1); saturates correctly at +-inf
  return 1.f - 2.f * __builtin_amdgcn_rcpf(1.f + __builtin_amdgcn_exp2f(2.88539008f * x));
}

// d_ws layout (ushort): W1[64][128] @0 | WRZ[128][128] @8192 (cols 0:64 = w_ih
// rows 0:128, cols 64:128 = w_hh rows 0:128) | WIN[64][64] @24576 (w_ih rows
// 128:192) | WHN[64][64] @28672 (w_hh rows 128:192) | W2[16][64] @32768.
__global__ void convert_weights(const float* __restrict__ fc1_w,
                                const float* __restrict__ w_ih,
                                const float* __restrict__ w_hh,
                                const float* __restrict__ fc2_w,
                                unsigned short* __restrict__ ws) {
  int i = blockIdx.x * 256 + threadIdx.x;
  if (i < 8192) {
    ws[i] = f2b(fc1_w[i]);
  } else if (i < 24576) {
    int j = i - 8192; int n = j >> 7; int k = j & 127;
    float v = (k < 64) ? w_ih[n * 64 + k] : w_hh[n * 64 + (k - 64)];
    ws[i] = f2b(v);
  } else if (i < 28672) {
    ws[i] = f2b(w_ih[8192 + (i - 24576)]);
  } else if (i < 32768) {
    ws[i] = f2b(w_hh[8192 + (i - 28672)]);
  } else if (i < 33792) {
    ws[i] = f2b(fc2_w[i - 32768]);
  }
}

__global__ __launch_bounds__(512) void gru_actor_main(
    const float* __restrict__ x, const float* __restrict__ hs,
    const int* __restrict__ am,
    const float* __restrict__ fc1_b, const float* __restrict__ b_ih,
    const float* __restrict__ b_hh, const float* __restrict__ fc2_b,
    const unsigned short* __restrict__ wb, float* __restrict__ out) {
  // per-wave 16x72 bf16 scratch (stride 72 keeps 16B alignment, conflict-floor reads)
  __shared__ unsigned short sb_all[8][16 * 72];
  const int tid  = threadIdx.x;
  const int wv   = tid >> 6;
  const int lane = tid & 63;
  const int col  = lane & 15;   // A-row / B-col / D-col index
  const int quad = lane >> 4;   // K-chunk / D-row-group index
  const int r0   = blockIdx.x * 128 + wv * 16;
  if (r0 >= BB) return;         // no barriers below -> early return is safe
  unsigned short* sb = sb_all[wv];

  const unsigned short* __restrict__ W1  = wb;
  const unsigned short* __restrict__ WRZ = wb + 8192;
  const unsigned short* __restrict__ WIN = wb + 24576;
  const unsigned short* __restrict__ WHN = wb + 28672;
  const unsigned short* __restrict__ W2  = wb + 32768;

  const f32x4 zero4 = {0.f, 0.f, 0.f, 0.f};

  // ---- Phase 1: a = tanh(x @ fc1_w^T + fc1_b) -> sbuf (bf16, A-layout src) ----
  f32x4 accA[4] = {zero4, zero4, zero4, zero4};
#pragma unroll
  for (int kt = 0; kt < 4; ++kt) {
    short8 af = load_cvt_frag(x + (r0 + col) * OBSN + kt * 32 + quad * 8);
#pragma unroll
    for (int nt = 0; nt < 4; ++nt) {
      short8 bf = *(const short8*)(W1 + (nt * 16 + col) * 128 + kt * 32 + quad * 8);
      accA[nt] = __builtin_amdgcn_mfma_f32_16x16x32_bf16(af, bf, accA[nt], 0, 0, 0);
    }
  }
#pragma unroll
  for (int nt = 0; nt < 4; ++nt) {
    float b1 = fc1_b[nt * 16 + col];
#pragma unroll
    for (int rg = 0; rg < 4; ++rg) {
      float a = ftanh(accA[nt][rg] + b1);
      sb[(quad * 4 + rg) * 72 + nt * 16 + col] = f2b(a);  // C-layout -> LDS
    }
  }
  __threadfence_block();  // wave-local LDS write->read ordering (lgkmcnt drain)

  // ---- Phase 2: gates. rz = [a,h] @ WRZ^T ; i_n = a @ WIN^T ; h_n = h @ WHN^T ----
  f32x4 rz[8]  = {zero4, zero4, zero4, zero4, zero4, zero4, zero4, zero4};
  f32x4 gin[4] = {zero4, zero4, zero4, zero4};
  f32x4 ghn[4] = {zero4, zero4, zero4, zero4};
#pragma unroll
  for (int kt = 0; kt < 2; ++kt) {  // K 0..63 : a
    short8 af = *(const short8*)(sb + col * 72 + kt * 32 + quad * 8);
#pragma unroll
    for (int nt = 0; nt < 8; ++nt) {
      short8 bf = *(const short8*)(WRZ + (nt * 16 + col) * 128 + kt * 32 + quad * 8);
      rz[nt] = __builtin_amdgcn_mfma_f32_16x16x32_bf16(af, bf, rz[nt], 0, 0, 0);
    }
#pragma unroll
    for (int nt = 0; nt < 4; ++nt) {
      short8 bf = *(const short8*)(WIN + (nt * 16 + col) * 64 + kt * 32 + quad * 8);
      gin[nt] = __builtin_amdgcn_mfma_f32_16x16x32_bf16(af, bf, gin[nt], 0, 0, 0);
    }
  }
#pragma unroll
  for (int kt = 0; kt < 2; ++kt) {  // K 64..127 : h
    short8 af = load_cvt_frag(hs + (r0 + col) * HD + kt * 32 + quad * 8);
#pragma unroll
    for (int nt = 0; nt < 8; ++nt) {
      short8 bf = *(const short8*)(WRZ + (nt * 16 + col) * 128 + 64 + kt * 32 + quad * 8);
      rz[nt] = __builtin_amdgcn_mfma_f32_16x16x32_bf16(af, bf, rz[nt], 0, 0, 0);
    }
#pragma unroll
    for (int nt = 0; nt < 4; ++nt) {
      short8 bf = *(const short8*)(WHN + (nt * 16 + col) * 64 + kt * 32 + quad * 8);
      ghn[nt] = __builtin_amdgcn_mfma_f32_16x16x32_bf16(af, bf, ghn[nt], 0, 0, 0);
    }
  }

  // ---- Gate elementwise + masked update; h_new -> global + sbuf ----
  const int rowbase = r0 + quad * 4;
  int amv[4];
#pragma unroll
  for (int rg = 0; rg < 4; ++rg) amv[rg] = am[rowbase + rg];
#pragma unroll
  for (int nt = 0; nt < 4; ++nt) {
    int c = nt * 16 + col;
    float br = b_ih[c] + b_hh[c];
    float bz = b_ih[64 + c] + b_hh[64 + c];
    float bi = b_ih[128 + c];
    float bh = b_hh[128 + c];
#pragma unroll
    for (int rg = 0; rg < 4; ++rg) {
      int row = rowbase + rg;
      float r = fsigmoid(rz[nt][rg] + br);
      float z = fsigmoid(rz[nt + 4][rg] + bz);
      float n = ftanh(gin[nt][rg] + bi + r * (ghn[nt][rg] + bh));
      float hprev = hs[row * HD + c];
      float hu = (1.f - z) * n + z * hprev;
      float hne = (amv[rg] != 0) ? hu : hprev;
      out[(size_t)BB * ADIM + (size_t)row * HD + c] = hne;  // new_hidden output
      sb[(quad * 4 + rg) * 72 + c] = f2b(hne);
    }
  }
  __threadfence_block();

  // ---- Phase 3: logits = h_new @ fc2_w^T + fc2_b ----
  f32x4 acc2 = zero4;
#pragma unroll
  for (int kt = 0; kt < 2; ++kt) {
    short8 af = *(const short8*)(sb + col * 72 + kt * 32 + quad * 8);
    short8 bf = *(const short8*)(W2 + col * 64 + kt * 32 + quad * 8);
    acc2 = __builtin_amdgcn_mfma_f32_16x16x32_bf16(af, bf, acc2, 0, 0, 0);
  }
  float b2 = fc2_b[col];
#pragma unroll
  for (int rg = 0; rg < 4; ++rg) {
    out[(size_t)(rowbase + rg) * ADIM + col] = acc2[rg] + b2;
  }
}

extern "C" void kernel_launch(void* const* d_in, const int* in_sizes, int n_in,
                              void* d_out, int out_size, void* d_ws, size_t ws_size,
                              hipStream_t stream) {
  const float* x     = (const float*)d_in[0];
  const float* hsp   = (const float*)d_in[1];
  const int*   amp   = (const int*)d_in[2];
  const float* fc1_w = (const float*)d_in[3];
  const float* fc1_b = (const float*)d_in[4];
  const float* w_ih  = (const float*)d_in[5];
  const float* w_hh  = (const float*)d_in[6];
  const float* b_ih  = (const float*)d_in[7];
  const float* b_hh  = (const float*)d_in[8];
  const float* fc2_w = (const float*)d_in[9];
  const float* fc2_b = (const float*)d_in[10];
  unsigned short* wb = (unsigned short*)d_ws;
  float* out = (float*)d_out;

  convert_weights<<<dim3(132), dim3(256), 0, stream>>>(fc1_w, w_ih, w_hh, fc2_w, wb);
  gru_actor_main<<<dim3((BB + 127) / 128), dim3(512), 0, stream>>>(
      x, hsp, amp, fc1_b, b_ih, b_hh, fc2_b, wb, out);
}